// Round 7
// baseline (200.532 us; speedup 1.0000x reference)
//
#include <hip/hip_runtime.h>
#include <hip/hip_bf16.h>

#define H 256
#define L2H 512
#define NLAYERS 4
#define VOCAB 50257

// d_out layout: logp[50257], hidden_new[4*256], attn_weights[256]  (dtype = flag)
#define OUT_LOGP 0
#define OUT_HID  50257
#define OUT_ATTN 51281

// ws layout (fp32 elements) — 2305 floats
#define WS_SCORE 0       // 256 attn scores (stc/ldc)
#define WS_BARS  256     // 256 uints: 16 counter lines, 64B apart (idx*16)
#define WS_APP   512     // 256 attn_applied accumulator (atomicAdd; zeroed by k_init)
#define WS_XA    768     // x0, x2 ping  (aliases PM after chain: all XA reads precede L_X4)
#define WS_XB    1024    // x1, x3 pong  (aliases PS after chain)
#define WS_PM    768
#define WS_PS    1024
#define WS_X4    1280    // final x, copy 0
#define WS_X4B   1536    // copy 1
#define WS_X4C   1792    // copy 2
#define WS_GO    2048    // 16 lines x 16 floats; u64 flag+payload at each line start
#define WS_FLAG  2304    // 1.0f => bf16 inputs ; 0.0f => fp32

// counter line ids (bars[id*16])
#define L_SCORE 0        // exp 8
#define L_APP   1        // exp 8
#define L_X0    2        // L_X(l) = 2+l ; L_X4 = 6 ; exp 8 each
#define L_LOG0  8        // lines 8..15: logits partials, exp 32 each (bx&7)

#define NCHAIN 8         // chain blocks
#define NBLK 256         // 1 block/CU; co-resident

typedef unsigned short u16;
typedef unsigned long long u64;

__device__ __forceinline__ float bf2f(u16 u) {
    return __uint_as_float(((unsigned int)u) << 16);
}

__device__ __forceinline__ u16 f2bf(float f) {
    unsigned int x = __float_as_uint(f);
    unsigned int r = x + 0x7fff + ((x >> 16) & 1);
    return (u16)(r >> 16);
}

// ---- dtype-polymorphic load/store helpers (plain, cached) ----
template<bool BF16>
__device__ __forceinline__ float ld1(const void* p, size_t i) {
    if (BF16) return bf2f(((const u16*)p)[i]);
    else      return ((const float*)p)[i];
}

template<bool BF16>
__device__ __forceinline__ void ld8(const void* p, size_t i, float* f) {
    if (BF16) {
        uint4 u = *(const uint4*)((const u16*)p + i);
        f[0] = bf2f(u.x & 0xffff); f[1] = bf2f(u.x >> 16);
        f[2] = bf2f(u.y & 0xffff); f[3] = bf2f(u.y >> 16);
        f[4] = bf2f(u.z & 0xffff); f[5] = bf2f(u.z >> 16);
        f[6] = bf2f(u.w & 0xffff); f[7] = bf2f(u.w >> 16);
    } else {
        const float4* q = (const float4*)((const float*)p + i);
        float4 a = q[0], b = q[1];
        f[0] = a.x; f[1] = a.y; f[2] = a.z; f[3] = a.w;
        f[4] = b.x; f[5] = b.y; f[6] = b.z; f[7] = b.w;
    }
}

template<bool BF16>
__device__ __forceinline__ void st(void* p, size_t i, float v) {
    if (BF16) ((u16*)p)[i] = f2bf(v);
    else      ((float*)p)[i] = v;
}

// ---- coherent (LLC) access for cross-block data ----
__device__ __forceinline__ float ldc(const float* p) {
    return __hip_atomic_load(const_cast<float*>(p), __ATOMIC_RELAXED, __HIP_MEMORY_SCOPE_AGENT);
}
__device__ __forceinline__ void stc(float* p, float v) {
    __hip_atomic_store(p, v, __ATOMIC_RELAXED, __HIP_MEMORY_SCOPE_AGENT);
}
__device__ __forceinline__ u64 ldcu(const u64* p) {
    return __hip_atomic_load(const_cast<u64*>(p), __ATOMIC_RELAXED, __HIP_MEMORY_SCOPE_AGENT);
}
__device__ __forceinline__ void stcu(u64* p, u64 v) {
    __hip_atomic_store(p, v, __ATOMIC_RELAXED, __HIP_MEMORY_SCOPE_AGENT);
}

// ---- counter barrier pieces (8 arrivals / 8 pollers per line in the chain) ----
__device__ __forceinline__ void arrive_line(unsigned* bars, int idx) {
    __syncthreads();   // drains vmcnt(0): block's coherent stores complete at LLC
    if (threadIdx.x == 0)
        __hip_atomic_fetch_add(&bars[idx * 16], 1u, __ATOMIC_RELAXED, __HIP_MEMORY_SCOPE_AGENT);
}
template<int SLP>
__device__ __forceinline__ void wait_line(unsigned* bars, int idx, unsigned exp) {
    if (threadIdx.x == 0) {
        while (__hip_atomic_load(&bars[idx * 16], __ATOMIC_RELAXED, __HIP_MEMORY_SCOPE_AGENT) < exp)
            __builtin_amdgcn_s_sleep(SLP);
    }
    __syncthreads();
}

// ---- GO-line poll (16 lines, <=16 pollers each; u64 = payload<<32 | stage) ----
template<int SLP>
__device__ __forceinline__ u64 poll_go(const u64* p, unsigned need) {
    u64 u = ldcu(p);
    while ((unsigned)(u & 0xffffffffull) < need) {
        __builtin_amdgcn_s_sleep(SLP);
        u = ldcu(p);
    }
    return u;
}

__device__ __forceinline__ float dot8_u4bf(uint4 u, const float* xf) {
    return bf2f(u.x & 0xffff)*xf[0] + bf2f(u.x >> 16)*xf[1]
         + bf2f(u.y & 0xffff)*xf[2] + bf2f(u.y >> 16)*xf[3]
         + bf2f(u.z & 0xffff)*xf[4] + bf2f(u.z >> 16)*xf[5]
         + bf2f(u.w & 0xffff)*xf[6] + bf2f(u.w >> 16)*xf[7];
}

// ---------------- K0: zero counters/GO/APP, sniff dtype ----------------
__global__ __launch_bounds__(256) void k_init(const void* emb, float* ws) {
    int tid = threadIdx.x;
    __hip_atomic_store((unsigned*)(ws + WS_BARS) + tid, 0u, __ATOMIC_RELAXED, __HIP_MEMORY_SCOPE_AGENT);
    __hip_atomic_store((unsigned*)(ws + WS_GO) + tid, 0u, __ATOMIC_RELAXED, __HIP_MEMORY_SCOPE_AGENT);
    __hip_atomic_store((unsigned*)(ws + WS_APP) + tid, 0u, __ATOMIC_RELAXED, __HIP_MEMORY_SCOPE_AGENT);
    if (tid < 64) {
        float b = fabsf(bf2f(((const u16*)emb)[tid]));
        #pragma unroll
        for (int off = 32; off; off >>= 1) b = fmaxf(b, __shfl_xor(b, off));
        if (tid == 0) ws[WS_FLAG] = (b < 1.0f) ? 1.0f : 0.0f;
    }
}

// streaming logits body (chain blocks + fp32 path): 25 rows per 32-lane group
template<bool BF16>
__device__ __forceinline__ void logits_stream(
    const void* __restrict__ out_w, const void* __restrict__ out_b,
    const float* xf, int grp, int l32, float* vs, float& m, float& s)
{
    #pragma unroll
    for (int it = 0; it < 3; ++it) {
        const int rb = it * 16384 + grp;
        float wf[8][8], bb[8];
        #pragma unroll
        for (int k = 0; k < 8; ++k) {
            ld8<BF16>(out_w, (size_t)(rb + (k << 11)) * H + l32 * 8, wf[k]);
            bb[k] = ld1<BF16>(out_b, rb + (k << 11));
        }
        #pragma unroll
        for (int k = 0; k < 8; ++k) {
            float v = wf[k][0]*xf[0] + wf[k][1]*xf[1] + wf[k][2]*xf[2] + wf[k][3]*xf[3]
                    + wf[k][4]*xf[4] + wf[k][5]*xf[5] + wf[k][6]*xf[6] + wf[k][7]*xf[7];
            #pragma unroll
            for (int off = 16; off; off >>= 1) v += __shfl_xor(v, off);
            v += bb[k];
            vs[it * 8 + k] = v;
            float mn = fmaxf(m, v);
            s = s * __expf(m - mn) + __expf(v - mn);
            m = mn;
        }
    }
    vs[24] = 0.f;
    if (grp < VOCAB - 49152) {
        int r = 49152 + grp;
        float wf[8]; ld8<BF16>(out_w, (size_t)r * H + l32 * 8, wf);
        float v = wf[0]*xf[0] + wf[1]*xf[1] + wf[2]*xf[2] + wf[3]*xf[3]
                + wf[4]*xf[4] + wf[5]*xf[5] + wf[6]*xf[6] + wf[7]*xf[7];
        #pragma unroll
        for (int off = 16; off; off >>= 1) v += __shfl_xor(v, off);
        v += ld1<BF16>(out_b, r);
        vs[24] = v;
        float mn = fmaxf(m, v);
        s = s * __expf(m - mn) + __expf(v - mn);
        m = mn;
    }
}

// ---------------- The whole network in one kernel ----------------
// Blocks 0..7: pre-logits chain (8-arrival counters; x/h staged in LDS).
// Blocks 8..255: prefetch their 25 out_w rows into registers, poll GO line.
// All blocks: logits -> PM/PS partial -> LOG fan-in (8 lines) -> block-0
// relay combines -> GO2(+c payload) fan-out (16 lines) -> rescale+store.
template<bool BF16>
__device__ __forceinline__ void pipeline(
    const int* __restrict__ tok, const void* __restrict__ emb,
    const void* __restrict__ hidden,
    const void* __restrict__ attn_w, const void* __restrict__ attn_b,
    const void* __restrict__ enc,
    const void* __restrict__ comb_w, const void* __restrict__ comb_b,
    const void* __restrict__ gwih, const void* __restrict__ gwhh,
    const void* __restrict__ gbih, const void* __restrict__ gbhh,
    const void* __restrict__ out_w, const void* __restrict__ out_b,
    float* __restrict__ ws, void* __restrict__ out)
{
    unsigned* bars = (unsigned*)(ws + WS_BARS);
    const int tid  = threadIdx.x;
    const int lane = tid & 63;
    const int wid  = tid >> 6;
    const int bx   = blockIdx.x;
    const size_t es = BF16 ? 2 : 4;

    const int grp = (bx << 3) | (tid >> 5);   // 0..2047
    const int l32 = tid & 31;

    __shared__ float lds[256];
    __shared__ float wsm[256];
    __shared__ float xsh[256];
    __shared__ float hsh[256];
    __shared__ float gd[192];
    __shared__ float cshare;

    float vs[25];
    float m = -1e30f, s = 0.f;

    if (bx < NCHAIN) {
        // ================= chain (blocks 0..7) =================
        const int rbase = bx * 32;
        const int j8 = lane * 8;
        const int tk = tok[0];

        // ---- P0: attn scores = concat(emb, h0) @ attn_w.T + attn_b ----
        {
            float wfa[8][8];
            #pragma unroll
            for (int k = 0; k < 8; ++k)
                ld8<BF16>(attn_w, (size_t)(rbase + wid * 8 + k) * L2H + j8, wfa[k]);
            float xin[8];
            if (lane < 32) ld8<BF16>(emb, (size_t)tk * H + j8, xin);
            else           ld8<BF16>(hidden, (size_t)(j8 - H), xin);
            #pragma unroll
            for (int k = 0; k < 8; ++k) {
                int r = rbase + wid * 8 + k;
                float v = 0.f;
                #pragma unroll
                for (int q = 0; q < 8; ++q) v += xin[q] * wfa[k][q];
                #pragma unroll
                for (int off = 32; off; off >>= 1) v += __shfl_xor(v, off);
                if (lane == 0) stc(ws + WS_SCORE + r, v + ld1<BF16>(attn_b, r));
            }
        }
        arrive_line(bars, L_SCORE);

        // ---- P1: replicated softmax + this block's 32-row apply slice ----
        {
            float ev[32];                       // preload enc slice under the wait
            #pragma unroll
            for (int k = 0; k < 32; ++k)
                ev[k] = ld1<BF16>(enc, (size_t)(rbase + k) * H + tid);
            wait_line<1>(bars, L_SCORE, NCHAIN);
            float sc = ldc(ws + WS_SCORE + tid);
            lds[tid] = sc; __syncthreads();
            for (int off = 128; off; off >>= 1) {
                if (tid < off) lds[tid] = fmaxf(lds[tid], lds[tid + off]);
                __syncthreads();
            }
            float M = lds[0]; __syncthreads();
            float e = __expf(sc - M);
            lds[tid] = e; __syncthreads();
            for (int off = 128; off; off >>= 1) {
                if (tid < off) lds[tid] += lds[tid + off];
                __syncthreads();
            }
            float w = e / lds[0];
            wsm[tid] = w; __syncthreads();
            if (bx == 0) st<BF16>(out, OUT_ATTN + tid, w);
            float acc = 0.f;
            #pragma unroll
            for (int k = 0; k < 32; ++k) acc += wsm[rbase + k] * ev[k];
            atomicAdd(&ws[WS_APP + tid], acc);
        }
        arrive_line(bars, L_APP);

        // ---- P2: x0 = relu(concat(emb, attn_applied) @ comb_w.T + comb_b) ----
        {
            float wfa[8][8];
            #pragma unroll
            for (int k = 0; k < 8; ++k)
                ld8<BF16>(comb_w, (size_t)(rbase + wid * 8 + k) * L2H + j8, wfa[k]);
            float xin[8];
            if (lane < 32) ld8<BF16>(emb, (size_t)tk * H + j8, xin);
            wait_line<1>(bars, L_APP, NCHAIN);
            xsh[tid] = ldc(ws + WS_APP + tid);   // stage once per block
            __syncthreads();
            if (lane >= 32) {
                #pragma unroll
                for (int q = 0; q < 8; ++q) xin[q] = xsh[j8 - H + q];
            }
            #pragma unroll
            for (int k = 0; k < 8; ++k) {
                int r = rbase + wid * 8 + k;
                float v = 0.f;
                #pragma unroll
                for (int q = 0; q < 8; ++q) v += xin[q] * wfa[k][q];
                #pragma unroll
                for (int off = 32; off; off >>= 1) v += __shfl_xor(v, off);
                if (lane == 0) stc(ws + WS_XA + r, fmaxf(v + ld1<BF16>(comb_b, r), 0.f));
            }
        }
        arrive_line(bars, L_X0);

        // ---- P3..P6: 4 GRU layers, thread-per-weight-row, LDS-staged x/h ----
        #pragma unroll 1
        for (int l = 0; l < NLAYERS; ++l) {
            const float* xin_p = ws + ((l & 1) ? WS_XB : WS_XA);
            const char* wih = (const char*)gwih + (size_t)l * 3 * H * H * es;
            const char* whh = (const char*)gwhh + (size_t)l * 3 * H * H * es;
            const char* bih = (const char*)gbih + (size_t)l * 3 * H * es;
            const char* bhh = (const char*)gbhh + (size_t)l * 3 * H * es;
            const char* hprev = (const char*)hidden + (size_t)l * H * es;
            char*       hout  = (char*)out + (size_t)(OUT_HID + l * H) * es;

            wait_line<1>(bars, L_X0 + l, NCHAIN);
            xsh[tid] = ldc(xin_p + tid);            // 8 blocks x 16/line: cheap
            hsh[tid] = ld1<BF16>(hprev, tid);
            __syncthreads();

            if (tid < 192) {
                int mat = tid / 96;                 // 0 = wih(x), 1 = whh(h)
                int rem = tid % 96;
                int g   = rem / 32;                 // gate 0=r,1=z,2=n
                int j   = rem % 32;
                const void* W = mat ? (const void*)whh : (const void*)wih;
                const float* xv = mat ? hsh : xsh;  // lane-uniform LDS broadcast reads
                size_t rowoff = (size_t)(g * H + rbase + j) * H;
                float acc = 0.f;
                #pragma unroll 16
                for (int c = 0; c < H; c += 8) {
                    float wf[8]; ld8<BF16>(W, rowoff + c, wf);
                    acc += wf[0]*xv[c]   + wf[1]*xv[c+1] + wf[2]*xv[c+2] + wf[3]*xv[c+3]
                         + wf[4]*xv[c+4] + wf[5]*xv[c+5] + wf[6]*xv[c+6] + wf[7]*xv[c+7];
                }
                gd[tid] = acc;
            }
            __syncthreads();
            if (tid < 32) {
                int i = rbase + tid;
                float r = 1.f / (1.f + __expf(-(gd[tid]      + ld1<BF16>(bih, i)
                                              + gd[96 + tid] + ld1<BF16>(bhh, i))));
                float z = 1.f / (1.f + __expf(-(gd[32 + tid]  + ld1<BF16>(bih, H + i)
                                              + gd[128 + tid] + ld1<BF16>(bhh, H + i))));
                float n = tanhf(gd[64 + tid] + ld1<BF16>(bih, 2 * H + i)
                              + r * (gd[160 + tid] + ld1<BF16>(bhh, 2 * H + i)));
                float hn = (1.f - z) * n + z * hsh[i];
                if (l < 3) stc(ws + ((l & 1) ? WS_XA : WS_XB) + i, hn);
                else { stc(ws + WS_X4 + i, hn); stc(ws + WS_X4B + i, hn); stc(ws + WS_X4C + i, hn); }
                st<BF16>(hout, i, hn);
            }
            arrive_line(bars, L_X0 + l + 1);
        }

        wait_line<1>(bars, L_X0 + 4, NCHAIN);
        if (bx == 0 && tid < 16)                    // GO1: x4 ready, 16 replica lines
            stcu((u64*)(ws + WS_GO + 16 * tid), 1ull);

        // stage x4 once per block, then stream this block's logits rows (cold)
        xsh[tid] = ldc(ws + WS_X4 + (bx % 3) * 256 + tid);
        __syncthreads();
        float xf[8];
        #pragma unroll
        for (int q = 0; q < 8; ++q) xf[q] = xsh[l32 * 8 + q];
        logits_stream<BF16>(out_w, out_b, xf, grp, l32, vs, m, s);
    } else {
        // ================= prefetch blocks (8..255) =================
        if constexpr (BF16) {
            uint4 pw[25]; float pb[25];
            #pragma unroll
            for (int it = 0; it < 3; ++it)
                #pragma unroll
                for (int k = 0; k < 8; ++k) {
                    int r = it * 16384 + (k << 11) + grp;
                    pw[it * 8 + k] = *(const uint4*)((const u16*)out_w + (size_t)r * H + l32 * 8);
                    pb[it * 8 + k] = ld1<true>(out_b, r);
                }
            if (grp < VOCAB - 49152) {
                int r = 49152 + grp;
                pw[24] = *(const uint4*)((const u16*)out_w + (size_t)r * H + l32 * 8);
                pb[24] = ld1<true>(out_b, r);
            } else { pw[24] = make_uint4(0, 0, 0, 0); pb[24] = 0.f; }

            if (tid == 0) (void)poll_go<2>((const u64*)(ws + WS_GO + 16 * (bx & 15)), 1u);
            __syncthreads();
            xsh[tid] = ldc(ws + WS_X4 + (bx % 3) * 256 + tid);
            __syncthreads();
            float xf[8];
            #pragma unroll
            for (int q = 0; q < 8; ++q) xf[q] = xsh[l32 * 8 + q];

            #pragma unroll
            for (int idx = 0; idx < 24; ++idx) {
                float v = dot8_u4bf(pw[idx], xf);
                #pragma unroll
                for (int off = 16; off; off >>= 1) v += __shfl_xor(v, off);
                v += pb[idx];
                vs[idx] = v;
                float mn = fmaxf(m, v);
                s = s * __expf(m - mn) + __expf(v - mn);
                m = mn;
            }
            vs[24] = 0.f;
            if (grp < VOCAB - 49152) {
                float v = dot8_u4bf(pw[24], xf);
                #pragma unroll
                for (int off = 16; off; off >>= 1) v += __shfl_xor(v, off);
                v += pb[24];
                vs[24] = v;
                float mn = fmaxf(m, v);
                s = s * __expf(m - mn) + __expf(v - mn);
                m = mn;
            }
        } else {
            if (tid == 0) (void)poll_go<2>((const u64*)(ws + WS_GO + 16 * (bx & 15)), 1u);
            __syncthreads();
            xsh[tid] = ldc(ws + WS_X4 + (bx % 3) * 256 + tid);
            __syncthreads();
            float xf[8];
            #pragma unroll
            for (int q = 0; q < 8; ++q) xf[q] = xsh[l32 * 8 + q];
            logits_stream<false>(out_w, out_b, xf, grp, l32, vs, m, s);
        }
    }

    // ---- merge the wave's two 32-lane groups, then 4 waves -> block partial ----
    {
        float mo = __shfl_xor(m, 32), so = __shfl_xor(s, 32);
        float M = fmaxf(m, mo);
        s = s * __expf(m - M) + so * __expf(mo - M);
        m = M;
    }
    if (lane == 0) { lds[wid] = m; lds[4 + wid] = s; }
    __syncthreads();
    if (tid == 0) {
        float M01 = fmaxf(lds[0], lds[1]);
        float S01 = lds[4] * __expf(lds[0] - M01) + lds[5] * __expf(lds[1] - M01);
        float M23 = fmaxf(lds[2], lds[3]);
        float S23 = lds[6] * __expf(lds[2] - M23) + lds[7] * __expf(lds[3] - M23);
        float Mx = fmaxf(M01, M23);
        float S  = S01 * __expf(M01 - Mx) + S23 * __expf(M23 - Mx);
        stc(ws + WS_PM + bx, Mx);
        stc(ws + WS_PS + bx, S);
    }
    arrive_line(bars, L_LOG0 + (bx & 7));   // 8 lines x 32 arrivals

    float c;
    if (bx == 0) {
        // relay: sole poller of LOG lines; sole reader of PM/PS
        if (tid < 8) {
            while (__hip_atomic_load(&bars[(L_LOG0 + tid) * 16],
                                     __ATOMIC_RELAXED, __HIP_MEMORY_SCOPE_AGENT) < 32u)
                __builtin_amdgcn_s_sleep(1);
        }
        __syncthreads();
        float mm = ldc(ws + WS_PM + tid);
        float ss = ldc(ws + WS_PS + tid);
        #pragma unroll
        for (int off = 32; off; off >>= 1) {
            float mo = __shfl_xor(mm, off), so = __shfl_xor(ss, off);
            float M = fmaxf(mm, mo);
            ss = ss * __expf(mm - M) + so * __expf(mo - M);
            mm = M;
        }
        if (lane == 0) { lds[wid] = mm; lds[4 + wid] = ss; }
        __syncthreads();
        if (tid == 0) {
            float M01 = fmaxf(lds[0], lds[1]);
            float S01 = lds[4] * __expf(lds[0] - M01) + lds[5] * __expf(lds[1] - M01);
            float M23 = fmaxf(lds[2], lds[3]);
            float S23 = lds[6] * __expf(lds[2] - M23) + lds[7] * __expf(lds[3] - M23);
            float Mx = fmaxf(M01, M23);
            float S  = S01 * __expf(M01 - Mx) + S23 * __expf(M23 - Mx);
            cshare = Mx + __logf(S);
        }
        __syncthreads();
        c = cshare;
        if (tid < 16)                        // GO2: c payload + stage 2
            stcu((u64*)(ws + WS_GO + 16 * tid),
                 ((u64)__float_as_uint(c) << 32) | 2ull);
    } else {
        if (tid == 0) {
            u64 u = poll_go<2>((const u64*)(ws + WS_GO + 16 * (bx & 15)), 2u);
            cshare = __uint_as_float((unsigned)(u >> 32));
        }
        __syncthreads();
        c = cshare;
    }

    // ---- rescale from registers + store logp ----
    if (l32 == 0) {
        #pragma unroll
        for (int it = 0; it < 3; ++it)
            #pragma unroll
            for (int k = 0; k < 8; ++k)
                st<BF16>(out, OUT_LOGP + it * 16384 + (k << 11) + grp, vs[it * 8 + k] - c);
        if (grp < VOCAB - 49152)
            st<BF16>(out, OUT_LOGP + 49152 + grp, vs[24] - c);
    }
}

__global__ __launch_bounds__(256, 1) void k_all(
    const int* __restrict__ tok, const void* __restrict__ emb,
    const void* __restrict__ hidden,
    const void* __restrict__ attn_w, const void* __restrict__ attn_b,
    const void* __restrict__ enc,
    const void* __restrict__ comb_w, const void* __restrict__ comb_b,
    const void* __restrict__ gwih, const void* __restrict__ gwhh,
    const void* __restrict__ gbih, const void* __restrict__ gbhh,
    const void* __restrict__ out_w, const void* __restrict__ out_b,
    float* __restrict__ ws, void* __restrict__ out)
{
    if (ws[WS_FLAG] > 0.5f)
        pipeline<true >(tok, emb, hidden, attn_w, attn_b, enc, comb_w, comb_b,
                        gwih, gwhh, gbih, gbhh, out_w, out_b, ws, out);
    else
        pipeline<false>(tok, emb, hidden, attn_w, attn_b, enc, comb_w, comb_b,
                        gwih, gwhh, gbih, gbhh, out_w, out_b, ws, out);
}

extern "C" void kernel_launch(void* const* d_in, const int* in_sizes, int n_in,
                              void* d_out, int out_size, void* d_ws, size_t ws_size,
                              hipStream_t stream) {
    const int* tok = (const int*)d_in[0];
    float* ws = (float*)d_ws;

    k_init<<<dim3(1), dim3(256), 0, stream>>>(d_in[3], ws);
    k_all<<<dim3(NBLK), dim3(256), 0, stream>>>(
        tok, d_in[3], d_in[1], d_in[4], d_in[5], d_in[2], d_in[6], d_in[7],
        d_in[8], d_in[9], d_in[10], d_in[11], d_in[12], d_in[13],
        ws, d_out);
}

// Round 8
// 160.431 us; speedup vs baseline: 1.2500x; 1.2500x over previous
//
#include <hip/hip_runtime.h>
#include <hip/hip_bf16.h>

#define H 256
#define L2H 512
#define NLAYERS 4
#define VOCAB 50257

// d_out layout: logp[50257], hidden_new[4*256], attn_weights[256]  (dtype = flag)
#define OUT_LOGP 0
#define OUT_HID  50257
#define OUT_ATTN 51281

// ws layout (fp32 elements) — 2305 floats
#define WS_SCORE 0       // 256 attn scores (stc once, staged-read)
#define WS_BARS  256     // 256 uints: 16 group lines x 16 phase slots
#define WS_APP   512     // 256 attn_applied accumulator (atomicAdd; zeroed by k_init)
#define WS_XA    768     // x0, x2 ; PM after chain (all XA reads precede PH_LOG writes)
#define WS_XB    1024    // x1, x3 ; PS after chain
#define WS_PM    768
#define WS_PS    1024
#define WS_X4    1280    // x4 replicas: 1280 / 1536 / 1792
#define WS_GO    2048    // 16 lines x 16 floats; u64 stage|payload at line start
#define WS_FLAG  2304    // 1.0f => bf16 inputs ; 0.0f => fp32

// phase slots within each of 16 group lines: bars[g*16 + ph]
#define PH_SCORE 0       // exp 4  (64 chain blocks)
#define PH_APP   1       // exp 1  (16 apply blocks, one per line)
#define PH_X0    2       // exp 4 ; PH_X0+l = x_l ready ; PH_X0+4 = x4
#define PH_LOG   7       // exp 16 (all 256 blocks)

#define NCHAIN 64
#define NBLK   256       // 1 block/CU; co-resident

typedef unsigned short u16;
typedef unsigned long long u64;

__device__ __forceinline__ float bf2f(u16 u) {
    return __uint_as_float(((unsigned int)u) << 16);
}

__device__ __forceinline__ u16 f2bf(float f) {
    unsigned int x = __float_as_uint(f);
    unsigned int r = x + 0x7fff + ((x >> 16) & 1);
    return (u16)(r >> 16);
}

// ---- dtype-polymorphic load/store helpers (plain, cached) ----
template<bool BF16>
__device__ __forceinline__ float ld1(const void* p, size_t i) {
    if (BF16) return bf2f(((const u16*)p)[i]);
    else      return ((const float*)p)[i];
}

template<bool BF16>
__device__ __forceinline__ float4 ld4(const void* p, size_t i) {
    if (BF16) {
        ushort4 w = *(const ushort4*)((const u16*)p + i);
        return make_float4(bf2f(w.x), bf2f(w.y), bf2f(w.z), bf2f(w.w));
    } else {
        return *(const float4*)((const float*)p + i);
    }
}

template<bool BF16>
__device__ __forceinline__ void ld8(const void* p, size_t i, float* f) {
    if (BF16) {
        uint4 u = *(const uint4*)((const u16*)p + i);
        f[0] = bf2f(u.x & 0xffff); f[1] = bf2f(u.x >> 16);
        f[2] = bf2f(u.y & 0xffff); f[3] = bf2f(u.y >> 16);
        f[4] = bf2f(u.z & 0xffff); f[5] = bf2f(u.z >> 16);
        f[6] = bf2f(u.w & 0xffff); f[7] = bf2f(u.w >> 16);
    } else {
        const float4* q = (const float4*)((const float*)p + i);
        float4 a = q[0], b = q[1];
        f[0] = a.x; f[1] = a.y; f[2] = a.z; f[3] = a.w;
        f[4] = b.x; f[5] = b.y; f[6] = b.z; f[7] = b.w;
    }
}

template<bool BF16>
__device__ __forceinline__ void st(void* p, size_t i, float v) {
    if (BF16) ((u16*)p)[i] = f2bf(v);
    else      ((float*)p)[i] = v;
}

// ---- coherent (LLC) access for cross-block data ----
__device__ __forceinline__ float ldc(const float* p) {
    return __hip_atomic_load(const_cast<float*>(p), __ATOMIC_RELAXED, __HIP_MEMORY_SCOPE_AGENT);
}
__device__ __forceinline__ void stc(float* p, float v) {
    __hip_atomic_store(p, v, __ATOMIC_RELAXED, __HIP_MEMORY_SCOPE_AGENT);
}
__device__ __forceinline__ u64 ldcu(const u64* p) {
    return __hip_atomic_load(const_cast<u64*>(p), __ATOMIC_RELAXED, __HIP_MEMORY_SCOPE_AGENT);
}
__device__ __forceinline__ void stcu(u64* p, u64 v) {
    __hip_atomic_store(p, v, __ATOMIC_RELAXED, __HIP_MEMORY_SCOPE_AGENT);
}

// ---- per-block u64 staging of a 256-float coherent region into LDS ----
// ONE pass per block (128 u64 loads) => <=512 LLC accesses per line device-wide,
// then all lanes read from LDS. Replaces per-lane ldc storms (the round-4/6 cost).
__device__ __forceinline__ void stage256(float* sh, const float* src, int tid) {
    if (tid < 128) {
        u64 u = ldcu((const u64*)src + tid);
        sh[2 * tid]     = __uint_as_float((unsigned)(u & 0xffffffffull));
        sh[2 * tid + 1] = __uint_as_float((unsigned)(u >> 32));
    }
    __syncthreads();
}

// ---- phase counters: arrive on own group line; 16 lanes poll all 16 lines ----
__device__ __forceinline__ void arrive_ph(unsigned* bars, int bx, int ph) {
    __syncthreads();   // drains vmcnt(0): block's coherent stores complete at LLC
    if (threadIdx.x == 0)
        __hip_atomic_fetch_add(&bars[(bx & 15) * 16 + ph], 1u,
                               __ATOMIC_RELAXED, __HIP_MEMORY_SCOPE_AGENT);
}
template<int SLP>
__device__ __forceinline__ void wait_ph(unsigned* bars, int ph, unsigned exp) {
    if (threadIdx.x < 16) {
        while (__hip_atomic_load(&bars[threadIdx.x * 16 + ph],
                                 __ATOMIC_RELAXED, __HIP_MEMORY_SCOPE_AGENT) < exp)
            __builtin_amdgcn_s_sleep(SLP);
    }
    __syncthreads();
}

// ---- GO-line poll (16 lines; u64 = payload<<32 | stage) ----
template<int SLP>
__device__ __forceinline__ u64 poll_go(const u64* p, unsigned need) {
    u64 u = ldcu(p);
    while ((unsigned)(u & 0xffffffffull) < need) {
        __builtin_amdgcn_s_sleep(SLP);
        u = ldcu(p);
    }
    return u;
}

__device__ __forceinline__ float dot8_u4bf(uint4 u, const float* xf) {
    return bf2f(u.x & 0xffff)*xf[0] + bf2f(u.x >> 16)*xf[1]
         + bf2f(u.y & 0xffff)*xf[2] + bf2f(u.y >> 16)*xf[3]
         + bf2f(u.z & 0xffff)*xf[4] + bf2f(u.z >> 16)*xf[5]
         + bf2f(u.w & 0xffff)*xf[6] + bf2f(u.w >> 16)*xf[7];
}

// ---------------- K0: zero counters/GO/APP, sniff dtype ----------------
__global__ __launch_bounds__(256) void k_init(const void* emb, float* ws) {
    int tid = threadIdx.x;
    __hip_atomic_store((unsigned*)(ws + WS_BARS) + tid, 0u, __ATOMIC_RELAXED, __HIP_MEMORY_SCOPE_AGENT);
    __hip_atomic_store((unsigned*)(ws + WS_GO) + tid, 0u, __ATOMIC_RELAXED, __HIP_MEMORY_SCOPE_AGENT);
    __hip_atomic_store((unsigned*)(ws + WS_APP) + tid, 0u, __ATOMIC_RELAXED, __HIP_MEMORY_SCOPE_AGENT);
    if (tid < 64) {
        float b = fabsf(bf2f(((const u16*)emb)[tid]));
        #pragma unroll
        for (int off = 32; off; off >>= 1) b = fmaxf(b, __shfl_xor(b, off));
        if (tid == 0) ws[WS_FLAG] = (b < 1.0f) ? 1.0f : 0.0f;
    }
}

// streaming logits body: 25 rows per 32-lane group, ILP-8 loads
template<bool BF16>
__device__ __forceinline__ void logits_stream(
    const void* __restrict__ out_w, const void* __restrict__ out_b,
    const float* xf, int grp, int l32, float* vs, float& m, float& s)
{
    #pragma unroll
    for (int it = 0; it < 3; ++it) {
        const int rb = it * 16384 + grp;
        float wf[8][8], bb[8];
        #pragma unroll
        for (int k = 0; k < 8; ++k) {
            ld8<BF16>(out_w, (size_t)(rb + (k << 11)) * H + l32 * 8, wf[k]);
            bb[k] = ld1<BF16>(out_b, rb + (k << 11));
        }
        #pragma unroll
        for (int k = 0; k < 8; ++k) {
            float v = wf[k][0]*xf[0] + wf[k][1]*xf[1] + wf[k][2]*xf[2] + wf[k][3]*xf[3]
                    + wf[k][4]*xf[4] + wf[k][5]*xf[5] + wf[k][6]*xf[6] + wf[k][7]*xf[7];
            #pragma unroll
            for (int off = 16; off; off >>= 1) v += __shfl_xor(v, off);
            v += bb[k];
            vs[it * 8 + k] = v;
            float mn = fmaxf(m, v);
            s = s * __expf(m - mn) + __expf(v - mn);
            m = mn;
        }
    }
    vs[24] = 0.f;
    if (grp < VOCAB - 49152) {
        int r = 49152 + grp;
        float wf[8]; ld8<BF16>(out_w, (size_t)r * H + l32 * 8, wf);
        float v = wf[0]*xf[0] + wf[1]*xf[1] + wf[2]*xf[2] + wf[3]*xf[3]
                + wf[4]*xf[4] + wf[5]*xf[5] + wf[6]*xf[6] + wf[7]*xf[7];
        #pragma unroll
        for (int off = 16; off; off >>= 1) v += __shfl_xor(v, off);
        v += ld1<BF16>(out_b, r);
        vs[24] = v;
        float mn = fmaxf(m, v);
        s = s * __expf(m - mn) + __expf(v - mn);
        m = mn;
    }
}

// ---------------- The whole network in one kernel ----------------
// Blocks 0..63: chain (wave-per-row, coalesced; round-6 structure) with
// LDS-staged cross-block reads. Blocks 64..255: out_w register prefetch
// (bf16), GO1-gated. LOG fan-in (16 lines) -> block-0 relay -> GO2 + c payload.
template<bool BF16>
__device__ __forceinline__ void pipeline(
    const int* __restrict__ tok, const void* __restrict__ emb,
    const void* __restrict__ hidden,
    const void* __restrict__ attn_w, const void* __restrict__ attn_b,
    const void* __restrict__ enc,
    const void* __restrict__ comb_w, const void* __restrict__ comb_b,
    const void* __restrict__ gwih, const void* __restrict__ gwhh,
    const void* __restrict__ gbih, const void* __restrict__ gbhh,
    const void* __restrict__ out_w, const void* __restrict__ out_b,
    float* __restrict__ ws, void* __restrict__ out)
{
    unsigned* bars = (unsigned*)(ws + WS_BARS);
    const int tid  = threadIdx.x;
    const int lane = tid & 63;
    const int wid  = tid >> 6;
    const int bx   = blockIdx.x;
    const size_t es = BF16 ? 2 : 4;

    const int grp = (bx << 3) | (tid >> 5);   // 0..2047
    const int l32 = tid & 31;

    __shared__ float lds[256];
    __shared__ float xsh[256];
    __shared__ float wsm[256];
    __shared__ float cshare;

    float vs[25];
    float m = -1e30f, s = 0.f;

    if (bx < NCHAIN) {
        // ================= chain (blocks 0..63) =================
        const int wv = (bx << 2) | wid;   // 0..255: row owned by this wave
        const int j8 = lane * 8;
        const int tk = tok[0];

        // ---- P0: attn scores = concat(emb, h0) @ attn_w.T + attn_b ----
        {
            float wf[8]; ld8<BF16>(attn_w, (size_t)wv * L2H + j8, wf);
            float xin[8];
            if (lane < 32) ld8<BF16>(emb, (size_t)tk * H + j8, xin);
            else           ld8<BF16>(hidden, (size_t)(j8 - H), xin);   // hidden[0]
            float v = 0.f;
            #pragma unroll
            for (int q = 0; q < 8; ++q) v += xin[q] * wf[q];
            #pragma unroll
            for (int off = 32; off; off >>= 1) v += __shfl_xor(v, off);
            if (lane == 0) stc(ws + WS_SCORE + wv, v + ld1<BF16>(attn_b, wv));
        }
        arrive_ph(bars, bx, PH_SCORE);

        // ---- P1 (blocks 0..15): staged softmax + 16-row apply slice ----
        if (bx < 16) {
            const int l0 = bx * 16;
            float ev[16];                       // preload enc slice under the wait
            #pragma unroll
            for (int k = 0; k < 16; ++k)
                ev[k] = ld1<BF16>(enc, (size_t)(l0 + k) * H + tid);
            wait_ph<1>(bars, PH_SCORE, 4);
            stage256(lds, ws + WS_SCORE, tid);  // one u64 pass per block
            float sc = lds[tid];
            __syncthreads();
            for (int off = 128; off; off >>= 1) {
                if (tid < off) lds[tid] = fmaxf(lds[tid], lds[tid + off]);
                __syncthreads();
            }
            float M = lds[0]; __syncthreads();
            float e = __expf(sc - M);
            lds[tid] = e; __syncthreads();
            for (int off = 128; off; off >>= 1) {
                if (tid < off) lds[tid] += lds[tid + off];
                __syncthreads();
            }
            float w = e / lds[0];
            wsm[tid] = w; __syncthreads();
            if (bx == 0) st<BF16>(out, OUT_ATTN + tid, w);
            float acc = 0.f;
            #pragma unroll
            for (int k = 0; k < 16; ++k) acc += wsm[l0 + k] * ev[k];
            atomicAdd(&ws[WS_APP + tid], acc);  // device-scope RMW at LLC
            arrive_ph(bars, bx, PH_APP);        // one block per line: exp 1
        }

        // ---- P2: x0 = relu(concat(emb, attn_applied) @ comb_w.T + comb_b) ----
        {
            float wf[8]; ld8<BF16>(comb_w, (size_t)wv * L2H + j8, wf);   // preload
            float xin[8];
            if (lane < 32) ld8<BF16>(emb, (size_t)tk * H + j8, xin);     // preload
            wait_ph<1>(bars, PH_APP, 1);
            stage256(xsh, ws + WS_APP, tid);
            if (lane >= 32) {
                #pragma unroll
                for (int q = 0; q < 8; ++q) xin[q] = xsh[j8 - H + q];
            }
            float v = 0.f;
            #pragma unroll
            for (int q = 0; q < 8; ++q) v += xin[q] * wf[q];
            #pragma unroll
            for (int off = 32; off; off >>= 1) v += __shfl_xor(v, off);
            if (lane == 0) stc(ws + WS_XA + wv, fmaxf(v + ld1<BF16>(comb_b, wv), 0.f));
        }
        arrive_ph(bars, bx, PH_X0);

        // ---- P3..P6: 4 GRU layers, wave-per-row (coalesced), staged x ----
        // x0@XA -> x1@XB -> x2@XA -> x3@XB -> x4 replicas
        const int e4 = lane * 4;
        #pragma unroll 1
        for (int l = 0; l < NLAYERS; ++l) {
            const float* xin_p = ws + ((l & 1) ? WS_XB : WS_XA);
            float*       xout  = ws + ((l & 1) ? WS_XA : WS_XB);
            const char* wih = (const char*)gwih + (size_t)l * 3 * H * H * es;
            const char* whh = (const char*)gwhh + (size_t)l * 3 * H * H * es;
            const char* bih = (const char*)gbih + (size_t)l * 3 * H * es;
            const char* bhh = (const char*)gbhh + (size_t)l * 3 * H * es;
            const char* hprev = (const char*)hidden + (size_t)l * H * es;
            char*       hout  = (char*)out + (size_t)(OUT_HID + l * H) * es;
            const int i = wv;

            // x-independent preloads BEFORE the wait (latency hides under it)
            float4 hv  = ld4<BF16>(hprev, e4);
            float4 wri = ld4<BF16>(wih, (size_t)(i        ) * H + e4);
            float4 wzi = ld4<BF16>(wih, (size_t)(H + i    ) * H + e4);
            float4 wni = ld4<BF16>(wih, (size_t)(2 * H + i) * H + e4);
            float4 wrh = ld4<BF16>(whh, (size_t)(i        ) * H + e4);
            float4 wzh = ld4<BF16>(whh, (size_t)(H + i    ) * H + e4);
            float4 wnh = ld4<BF16>(whh, (size_t)(2 * H + i) * H + e4);

            wait_ph<1>(bars, PH_X0 + l, 4);
            stage256(xsh, xin_p, tid);

            float4 xv;
            xv.x = xsh[e4]; xv.y = xsh[e4 + 1]; xv.z = xsh[e4 + 2]; xv.w = xsh[e4 + 3];

            float a = wri.x * xv.x + wri.y * xv.y + wri.z * xv.z + wri.w * xv.w
                    + wrh.x * hv.x + wrh.y * hv.y + wrh.z * hv.z + wrh.w * hv.w;
            float b = wzi.x * xv.x + wzi.y * xv.y + wzi.z * xv.z + wzi.w * xv.w
                    + wzh.x * hv.x + wzh.y * hv.y + wzh.z * hv.z + wzh.w * hv.w;
            float c = wni.x * xv.x + wni.y * xv.y + wni.z * xv.z + wni.w * xv.w;
            float d = wnh.x * hv.x + wnh.y * hv.y + wnh.z * hv.z + wnh.w * hv.w;

            #pragma unroll
            for (int off = 32; off; off >>= 1) {
                a += __shfl_xor(a, off);
                b += __shfl_xor(b, off);
                c += __shfl_xor(c, off);
                d += __shfl_xor(d, off);
            }
            if (lane == 0) {
                float r = 1.f / (1.f + __expf(-(a + ld1<BF16>(bih, i) + ld1<BF16>(bhh, i))));
                float z = 1.f / (1.f + __expf(-(b + ld1<BF16>(bih, H + i) + ld1<BF16>(bhh, H + i))));
                float n = tanhf(c + ld1<BF16>(bih, 2 * H + i) + r * (d + ld1<BF16>(bhh, 2 * H + i)));
                float hold = ld1<BF16>(hprev, i);
                float hn = (1.f - z) * n + z * hold;
                if (l < 3) stc(xout + i, hn);
                else {
                    stc(ws + WS_X4 + i, hn);
                    stc(ws + WS_X4 + 256 + i, hn);
                    stc(ws + WS_X4 + 512 + i, hn);
                }
                st<BF16>(hout, i, hn);
            }
            arrive_ph(bars, bx, PH_X0 + l + 1);
        }

        wait_ph<1>(bars, PH_X0 + 4, 4);
        if (bx < 16 && tid == 0)                // GO1: block g publishes line g
            stcu((u64*)(ws + WS_GO + 16 * bx), 1ull);

        // chain blocks stream their logits slice (LLC-warm from prefetchers)
        stage256(xsh, ws + WS_X4 + (bx % 3) * 256, tid);
        float xf[8];
        #pragma unroll
        for (int q = 0; q < 8; ++q) xf[q] = xsh[l32 * 8 + q];
        logits_stream<BF16>(out_w, out_b, xf, grp, l32, vs, m, s);
    } else {
        // ================= prefetch blocks (64..255) =================
        if constexpr (BF16) {
            uint4 pw[25]; float pb[25];
            #pragma unroll
            for (int it = 0; it < 3; ++it)
                #pragma unroll
                for (int k = 0; k < 8; ++k) {
                    int r = it * 16384 + (k << 11) + grp;
                    pw[it * 8 + k] = *(const uint4*)((const u16*)out_w + (size_t)r * H + l32 * 8);
                    pb[it * 8 + k] = ld1<true>(out_b, r);
                }
            if (grp < VOCAB - 49152) {
                int r = 49152 + grp;
                pw[24] = *(const uint4*)((const u16*)out_w + (size_t)r * H + l32 * 8);
                pb[24] = ld1<true>(out_b, r);
            } else { pw[24] = make_uint4(0, 0, 0, 0); pb[24] = 0.f; }

            if (tid == 0) (void)poll_go<2>((const u64*)(ws + WS_GO + 16 * (bx & 15)), 1u);
            __syncthreads();
            stage256(xsh, ws + WS_X4 + (bx % 3) * 256, tid);
            float xf[8];
            #pragma unroll
            for (int q = 0; q < 8; ++q) xf[q] = xsh[l32 * 8 + q];

            #pragma unroll
            for (int idx = 0; idx < 24; ++idx) {
                float v = dot8_u4bf(pw[idx], xf);
                #pragma unroll
                for (int off = 16; off; off >>= 1) v += __shfl_xor(v, off);
                v += pb[idx];
                vs[idx] = v;
                float mn = fmaxf(m, v);
                s = s * __expf(m - mn) + __expf(v - mn);
                m = mn;
            }
            vs[24] = 0.f;
            if (grp < VOCAB - 49152) {
                float v = dot8_u4bf(pw[24], xf);
                #pragma unroll
                for (int off = 16; off; off >>= 1) v += __shfl_xor(v, off);
                v += pb[24];
                vs[24] = v;
                float mn = fmaxf(m, v);
                s = s * __expf(m - mn) + __expf(v - mn);
                m = mn;
            }
        } else {
            if (tid == 0) (void)poll_go<2>((const u64*)(ws + WS_GO + 16 * (bx & 15)), 1u);
            __syncthreads();
            stage256(xsh, ws + WS_X4 + (bx % 3) * 256, tid);
            float xf[8];
            #pragma unroll
            for (int q = 0; q < 8; ++q) xf[q] = xsh[l32 * 8 + q];
            logits_stream<false>(out_w, out_b, xf, grp, l32, vs, m, s);
        }
    }

    // ---- merge the wave's two 32-lane groups, then 4 waves -> block partial ----
    {
        float mo = __shfl_xor(m, 32), so = __shfl_xor(s, 32);
        float M = fmaxf(m, mo);
        s = s * __expf(m - M) + so * __expf(mo - M);
        m = M;
    }
    __syncthreads();
    if (lane == 0) { lds[wid] = m; lds[4 + wid] = s; }
    __syncthreads();
    if (tid == 0) {
        float M01 = fmaxf(lds[0], lds[1]);
        float S01 = lds[4] * __expf(lds[0] - M01) + lds[5] * __expf(lds[1] - M01);
        float M23 = fmaxf(lds[2], lds[3]);
        float S23 = lds[6] * __expf(lds[2] - M23) + lds[7] * __expf(lds[3] - M23);
        float Mx = fmaxf(M01, M23);
        float S  = S01 * __expf(M01 - Mx) + S23 * __expf(M23 - Mx);
        stc(ws + WS_PM + bx, Mx);   // aliases XA (dead: last XA read was x2 staging)
        stc(ws + WS_PS + bx, S);    // aliases XB
    }
    arrive_ph(bars, bx, PH_LOG);    // 256 arrivals over 16 lines (16 each)

    float c;
    if (bx == 0) {
        // relay: sole poller of LOG lines; sole reader of PM/PS
        if (tid < 16) {
            while (__hip_atomic_load(&bars[tid * 16 + PH_LOG],
                                     __ATOMIC_RELAXED, __HIP_MEMORY_SCOPE_AGENT) < 16u)
                __builtin_amdgcn_s_sleep(1);
        }
        __syncthreads();
        float mm = ldc(ws + WS_PM + tid);
        float ss = ldc(ws + WS_PS + tid);
        #pragma unroll
        for (int off = 32; off; off >>= 1) {
            float mo = __shfl_xor(mm, off), so = __shfl_xor(ss, off);
            float M = fmaxf(mm, mo);
            ss = ss * __expf(mm - M) + so * __expf(mo - M);
            mm = M;
        }
        if (lane == 0) { lds[wid] = mm; lds[4 + wid] = ss; }
        __syncthreads();
        if (tid == 0) {
            float M01 = fmaxf(lds[0], lds[1]);
            float S01 = lds[4] * __expf(lds[0] - M01) + lds[5] * __expf(lds[1] - M01);
            float M23 = fmaxf(lds[2], lds[3]);
            float S23 = lds[6] * __expf(lds[2] - M23) + lds[7] * __expf(lds[3] - M23);
            float Mx = fmaxf(M01, M23);
            float S  = S01 * __expf(M01 - Mx) + S23 * __expf(M23 - Mx);
            cshare = Mx + __logf(S);
        }
        __syncthreads();
        c = cshare;
        if (tid < 16)                           // GO2: stage 2 + c payload
            stcu((u64*)(ws + WS_GO + 16 * tid),
                 ((u64)__float_as_uint(c) << 32) | 2ull);
    } else {
        if (tid == 0) {
            u64 u = poll_go<2>((const u64*)(ws + WS_GO + 16 * (bx & 15)), 2u);
            cshare = __uint_as_float((unsigned)(u >> 32));
        }
        __syncthreads();
        c = cshare;
    }

    // ---- rescale from registers + store logp ----
    if (l32 == 0) {
        #pragma unroll
        for (int it = 0; it < 3; ++it)
            #pragma unroll
            for (int k = 0; k < 8; ++k)
                st<BF16>(out, OUT_LOGP + it * 16384 + (k << 11) + grp, vs[it * 8 + k] - c);
        if (grp < VOCAB - 49152)
            st<BF16>(out, OUT_LOGP + 49152 + grp, vs[24] - c);
    }
}

__global__ __launch_bounds__(256, 1) void k_all(
    const int* __restrict__ tok, const void* __restrict__ emb,
    const void* __restrict__ hidden,
    const void* __restrict__ attn_w, const void* __restrict__ attn_b,
    const void* __restrict__ enc,
    const void* __restrict__ comb_w, const void* __restrict__ comb_b,
    const void* __restrict__ gwih, const void* __restrict__ gwhh,
    const void* __restrict__ gbih, const void* __restrict__ gbhh,
    const void* __restrict__ out_w, const void* __restrict__ out_b,
    float* __restrict__ ws, void* __restrict__ out)
{
    if (ws[WS_FLAG] > 0.5f)
        pipeline<true >(tok, emb, hidden, attn_w, attn_b, enc, comb_w, comb_b,
                        gwih, gwhh, gbih, gbhh, out_w, out_b, ws, out);
    else
        pipeline<false>(tok, emb, hidden, attn_w, attn_b, enc, comb_w, comb_b,
                        gwih, gwhh, gbih, gbhh, out_w, out_b, ws, out);
}

extern "C" void kernel_launch(void* const* d_in, const int* in_sizes, int n_in,
                              void* d_out, int out_size, void* d_ws, size_t ws_size,
                              hipStream_t stream) {
    const int* tok = (const int*)d_in[0];
    float* ws = (float*)d_ws;

    k_init<<<dim3(1), dim3(256), 0, stream>>>(d_in[3], ws);
    k_all<<<dim3(NBLK), dim3(256), 0, stream>>>(
        tok, d_in[3], d_in[1], d_in[4], d_in[5], d_in[2], d_in[6], d_in[7],
        d_in[8], d_in[9], d_in[10], d_in[11], d_in[12], d_in[13],
        ws, d_out);
}